// Round 1
// baseline (304.369 us; speedup 1.0000x reference)
//
#include <hip/hip_runtime.h>

// DAGMixer: per (b,t) row of H=2048:
//   logit = dot(orig_row, W_o) + dot(dag_row, W_d) + b
//   gate  = sigmoid(logit)
//   mixed = orig + gate * (dag - orig)
// Outputs concatenated: mixed (B*T*H floats) then gate (B*T floats).
//
// One 256-thread block per row. Each thread holds 8 elems of each input in
// registers (2x float4), so inputs are read exactly once from HBM.

constexpr int H_DIM   = 2048;
constexpr int BLOCK   = 256;
constexpr int VEC_PER = H_DIM / 4 / BLOCK;   // 2 float4 per thread per tensor

__global__ __launch_bounds__(BLOCK) void dagmixer_fused(
    const float* __restrict__ orig,
    const float* __restrict__ dag,
    const float* __restrict__ Wg,      // [2*H] : W_o then W_d
    const float* __restrict__ bg,      // [1]
    float* __restrict__ mixed,         // [rows*H]
    float* __restrict__ gate_out)      // [rows]
{
    const int row  = blockIdx.x;
    const int t    = threadIdx.x;
    const long long base = (long long)row * H_DIM;

    const float4* o4  = reinterpret_cast<const float4*>(orig + base);
    const float4* d4  = reinterpret_cast<const float4*>(dag + base);
    const float4* wo4 = reinterpret_cast<const float4*>(Wg);
    const float4* wd4 = reinterpret_cast<const float4*>(Wg + H_DIM);

    float4 o[VEC_PER], d[VEC_PER];
    float partial = 0.0f;

#pragma unroll
    for (int i = 0; i < VEC_PER; ++i) {
        const int idx = t + i * BLOCK;        // coalesced: consecutive lanes -> consecutive float4
        o[i] = o4[idx];
        d[i] = d4[idx];
        const float4 wo = wo4[idx];           // 16KB total, L1/L2 resident
        const float4 wd = wd4[idx];
        partial += o[i].x * wo.x + o[i].y * wo.y + o[i].z * wo.z + o[i].w * wo.w;
        partial += d[i].x * wd.x + d[i].y * wd.y + d[i].z * wd.z + d[i].w * wd.w;
    }

    // wave (64-lane) butterfly reduce
#pragma unroll
    for (int off = 32; off > 0; off >>= 1)
        partial += __shfl_down(partial, off, 64);

    // cross-wave reduce via tiny LDS (4 waves)
    __shared__ float wsum[BLOCK / 64];
    const int wave = t >> 6;
    const int lane = t & 63;
    if (lane == 0) wsum[wave] = partial;
    __syncthreads();

    float logit = wsum[0] + wsum[1] + wsum[2] + wsum[3] + bg[0];
    const float gate = 1.0f / (1.0f + __expf(-logit));

    float4* m4 = reinterpret_cast<float4*>(mixed + base);
#pragma unroll
    for (int i = 0; i < VEC_PER; ++i) {
        const int idx = t + i * BLOCK;
        float4 m;
        m.x = o[i].x + gate * (d[i].x - o[i].x);
        m.y = o[i].y + gate * (d[i].y - o[i].y);
        m.z = o[i].z + gate * (d[i].z - o[i].z);
        m.w = o[i].w + gate * (d[i].w - o[i].w);
        m4[idx] = m;
    }

    if (t == 0) gate_out[row] = gate;
}

extern "C" void kernel_launch(void* const* d_in, const int* in_sizes, int n_in,
                              void* d_out, int out_size, void* d_ws, size_t ws_size,
                              hipStream_t stream) {
    const float* orig = (const float*)d_in[0];
    const float* dag  = (const float*)d_in[1];
    const float* Wg   = (const float*)d_in[2];
    const float* bg   = (const float*)d_in[3];

    const int total = in_sizes[0];            // B*T*H
    const int rows  = total / H_DIM;          // B*T = 16384

    float* mixed    = (float*)d_out;
    float* gate_out = (float*)d_out + (long long)total;

    dagmixer_fused<<<rows, BLOCK, 0, stream>>>(orig, dag, Wg, bg, mixed, gate_out);
}